// Round 8
// baseline (257.337 us; speedup 1.0000x reference)
//
#include <hip/hip_runtime.h>
#include <hip/hip_bf16.h>
#include <stdint.h>

#define DIMM  1024
#define NHEAD 16
#define DHEAD 64
#define BB    2
#define SQL   2048
#define SKL   4096
#define KVW   2048   // kv row width = 2*INNER
#define NT    (SKL / 64)

typedef __attribute__((ext_vector_type(8))) short short8;
typedef __attribute__((ext_vector_type(4))) float f32x4;
typedef __attribute__((ext_vector_type(16))) float f32x16;
typedef __attribute__((ext_vector_type(4))) unsigned short us4;

typedef const __attribute__((address_space(1))) uint32_t gu32_t;
typedef __attribute__((address_space(3))) uint32_t lu32_t;

#define GLDS16(gp, lp) __builtin_amdgcn_global_load_lds((gu32_t*)(gp), (lu32_t*)(lp), 16, 0, 0)

static __device__ __forceinline__ unsigned short f2bf(float f) {
  union { float f; uint32_t u; } v; v.f = f;
  uint32_t r = v.u + 0x7fffu + ((v.u >> 16) & 1u);
  return (unsigned short)(r >> 16);
}

// ---------- weight transpose + cast: in f32 [K][N] -> out bf16 [N][K] ----------
__global__ __launch_bounds__(256) void k_transpose_cast(const float* __restrict__ in,
                                                        unsigned short* __restrict__ out,
                                                        int K, int N) {
  __shared__ float tile[32][33];
  int n0 = blockIdx.x * 32, k0 = blockIdx.y * 32;
  int tx = threadIdx.x, ty = threadIdx.y;
  #pragma unroll
  for (int i = 0; i < 4; i++)
    tile[ty + i * 8][tx] = in[(size_t)(k0 + ty + i * 8) * N + n0 + tx];
  __syncthreads();
  #pragma unroll
  for (int i = 0; i < 4; i++)
    out[(size_t)(n0 + ty + i * 8) * K + k0 + tx] = f2bf(tile[tx][ty + i * 8]);
}

// ---------- elementwise f32 -> bf16 (vectorized) ----------
__global__ __launch_bounds__(256) void k_cast(const float* __restrict__ in,
                                              unsigned short* __restrict__ out) {
  size_t i = (size_t)(blockIdx.x * 256 + threadIdx.x) * 4;
  float4 v = *(const float4*)(in + i);
  us4 o;
  o.x = f2bf(v.x); o.y = f2bf(v.y); o.z = f2bf(v.z); o.w = f2bf(v.w);
  *(us4*)(out + i) = o;
}

// ---------- LayerNorm + cast bf16: one block per row ----------
__global__ __launch_bounds__(256) void k_ln(const float* __restrict__ x,
                                            const float* __restrict__ gamma,
                                            const float* __restrict__ beta,
                                            unsigned short* __restrict__ out) {
  const int row = blockIdx.x, tid = threadIdx.x;
  const float* xr = x + (size_t)row * DIMM;
  float4 v = *(const float4*)(xr + tid * 4);
  float s = v.x + v.y + v.z + v.w;
  float ss = v.x * v.x + v.y * v.y + v.z * v.z + v.w * v.w;
  #pragma unroll
  for (int m = 1; m < 64; m <<= 1) {
    s += __shfl_xor(s, m);
    ss += __shfl_xor(ss, m);
  }
  __shared__ float red[8];
  const int wid = tid >> 6, lane = tid & 63;
  if (lane == 0) { red[wid] = s; red[4 + wid] = ss; }
  __syncthreads();
  s = red[0] + red[1] + red[2] + red[3];
  ss = red[4] + red[5] + red[6] + red[7];
  float mu = s * (1.0f / DIMM);
  float var = ss * (1.0f / DIMM) - mu * mu;
  float rstd = rsqrtf(var + 1e-5f);
  float4 g = *(const float4*)(gamma + tid * 4);
  float4 bt = *(const float4*)(beta + tid * 4);
  us4 o;
  o.x = f2bf((v.x - mu) * rstd * g.x + bt.x);
  o.y = f2bf((v.y - mu) * rstd * g.y + bt.y);
  o.z = f2bf((v.z - mu) * rstd * g.z + bt.z);
  o.w = f2bf((v.w - mu) * rstd * g.w + bt.w);
  *(us4*)(out + (size_t)row * DIMM + tid * 4) = o;
}

// ---------- 128x128x32 bf16 GEMM, B^T layout, 2-phase gload_lds pipeline ----------
// MODE 0: bf16 out.  MODE 1: f32 out, (acc + bias[col]) * tanh(gate[0]).
template<int MODE>
__global__ __launch_bounds__(256) void k_gemm_bt(const unsigned short* __restrict__ A,
                                                 const unsigned short* __restrict__ BT,
                                                 void* __restrict__ Cv,
                                                 int M, int N, int K,
                                                 const float* __restrict__ bias,
                                                 const float* __restrict__ gate) {
  __shared__ unsigned short lA[2][128 * 32];
  __shared__ unsigned short lB[2][128 * 32];
  const int tid = threadIdx.x;
  const int wid = tid >> 6, lane = tid & 63;
  const int kg = lane >> 4, lr = lane & 15;
  const int wr = wid >> 1, wc = wid & 1;
  const int im = blockIdx.x, in_ = blockIdx.y;
  const int nt = K >> 5;
  const size_t baseA = (size_t)im * 128 * K;
  const size_t baseB = (size_t)in_ * 128 * K;

  f32x4 acc[4][4];
  #pragma unroll
  for (int m = 0; m < 4; m++)
    #pragma unroll
    for (int n = 0; n < 4; n++) {
      f32x4 z = {0.0f, 0.0f, 0.0f, 0.0f};
      acc[m][n] = z;
    }

  // staging: LDS linear, global source pre-swizzled (granule ^ ((row>>1)&3))
  auto GSTAGE = [&](int bufi, int t) {
    int k0 = t << 5;
    #pragma unroll
    for (int j = 0; j < 2; j++) {
      int e = wid * 1024 + j * 512 + lane * 8;
      int row = e >> 5;
      int g = (e >> 3) & 3;
      int col = (g ^ ((row >> 1) & 3)) << 3;
      GLDS16(A + baseA + (size_t)row * K + k0 + col, &lA[bufi][e]);
      GLDS16(BT + baseB + (size_t)row * K + k0 + col, &lB[bufi][e]);
    }
  };

  GSTAGE(0, 0);
  __syncthreads();
  int buf = 0;
  for (int t = 0; t < nt; t++) {
    if (t + 1 < nt) GSTAGE(buf ^ 1, t + 1);
    short8 a[4], b[4];
    #pragma unroll
    for (int m = 0; m < 4; m++) {
      int row = wr * 64 + m * 16 + lr;
      a[m] = *(const short8*)&lA[buf][row * 32 + ((kg ^ ((row >> 1) & 3)) << 3)];
    }
    #pragma unroll
    for (int n = 0; n < 4; n++) {
      int row = wc * 64 + n * 16 + lr;
      b[n] = *(const short8*)&lB[buf][row * 32 + ((kg ^ ((row >> 1) & 3)) << 3)];
    }
    #pragma unroll
    for (int m = 0; m < 4; m++)
      #pragma unroll
      for (int n = 0; n < 4; n++)
        acc[m][n] = __builtin_amdgcn_mfma_f32_16x16x32_bf16(a[m], b[n], acc[m][n], 0, 0, 0);
    __syncthreads();
    buf ^= 1;
  }

  const int r0 = im * 128 + wr * 64;
  const int c0 = in_ * 128 + wc * 64;
  if constexpr (MODE == 0) {
    unsigned short* C = (unsigned short*)Cv;
    #pragma unroll
    for (int m = 0; m < 4; m++)
      #pragma unroll
      for (int n = 0; n < 4; n++)
        #pragma unroll
        for (int j = 0; j < 4; j++)
          C[(size_t)(r0 + m * 16 + kg * 4 + j) * N + c0 + n * 16 + lr] = f2bf(acc[m][n][j]);
  } else {
    float* C = (float*)Cv;
    float gl = tanhf(gate[0]);
    #pragma unroll
    for (int m = 0; m < 4; m++)
      #pragma unroll
      for (int n = 0; n < 4; n++)
        #pragma unroll
        for (int j = 0; j < 4; j++) {
          int col = c0 + n * 16 + lr;
          C[(size_t)(r0 + m * 16 + kg * 4 + j) * N + col] = (acc[m][n][j] + bias[col]) * gl;
        }
  }
}

// ---------- flash attention v8 ----------
// 64 q/block, 2 waves x 32q, 128 threads, grid 1024 = 4 blocks/CU, LDS 32KB.
// 32x32x16 MFMA. Swapped QK^T (A=K, B=Q^T) -> C col=lane&31=q, rows=keys per
// m74 layout. P->PV-A-frag redistribution fully in-register: cvt_pk pairs +
// v_permlane32_swap_b32 (low/high half exchange) -- no sP LDS roundtrip.
// K staged swizzled for b128 reads; V staged subtiled for ds_read_b64_tr_b16.
__global__ __launch_bounds__(128) void k_attn(const unsigned short* __restrict__ Q,
                                              const unsigned short* __restrict__ KV,
                                              unsigned short* __restrict__ O) {
  __shared__ unsigned short sK[2][64 * 64];   // [key][d], granule-swizzled via source
  __shared__ unsigned short sV[2][64 * 64];   // subtiled [key/4][d/16][4][16]

  const int tid = threadIdx.x;
  const int wid = tid >> 6, lane = tid & 63;
  const int l31 = lane & 31, hi = lane >> 5;
  const int qb = blockIdx.x, bh = blockIdx.y;
  const int b = bh >> 4, h = bh & 15;

  const unsigned short* Qp = Q + (size_t)b * SQL * DIMM + h * DHEAD;
  const unsigned short* Kp = KV + (size_t)b * SKL * KVW + h * DHEAD;
  const unsigned short* Vp = Kp + DIMM;

  const int qr0 = qb * 64 + wid * 32;

  // ---- staging geometry (loop-invariant), 128 threads x 4 granules each ----
  const unsigned short* ksrc[4]; int kdst[4];
  const unsigned short* vsrc[4]; int vdst[4];
  #pragma unroll
  for (int j = 0; j < 4; j++) {
    int e = (tid + j * 128) * 8;
    int row = e >> 6;
    int col = (((e >> 3) & 7) ^ (row & 7)) << 3;
    ksrc[j] = Kp + (size_t)row * KVW + col;
    kdst[j] = e;
    int g = tid + j * 128;
    int key = (g >> 5) * 4 + ((g >> 1) & 3);
    int d0v = ((g >> 3) & 3) * 16 + (g & 1) * 8;
    vsrc[j] = Vp + (size_t)key * KVW + d0v;
    vdst[j] = g * 8;
  }

  auto STAGE = [&](int bufi, int kt) {
    size_t off = (size_t)kt * 64 * KVW;
    #pragma unroll
    for (int j = 0; j < 4; j++) GLDS16(ksrc[j] + off, &sK[bufi][kdst[j]]);
    #pragma unroll
    for (int j = 0; j < 4; j++) GLDS16(vsrc[j] + off, &sV[bufi][vdst[j]]);
  };

  // Q fragments (B-operand of 32x32x16): lane holds Q[qr0+l31][t*16+hi*8 ..+7],
  // pre-scaled by SCALE*log2(e) so QK^T emits log2-domain logits.
  short8 qa[4];
  #pragma unroll
  for (int t = 0; t < 4; t++) {
    short8 v = *(const short8*)(Qp + (size_t)(qr0 + l31) * DIMM + t * 16 + hi * 8);
    #pragma unroll
    for (int j = 0; j < 8; j++) {
      union { float f; uint32_t u; } c;
      c.u = ((uint32_t)(unsigned short)v[j]) << 16;
      v[j] = (short)f2bf(c.f * 0.1803368801111f);  // 0.125 * log2(e)
    }
    qa[t] = v;
  }

  f32x16 oacc[2];
  #pragma unroll
  for (int d2 = 0; d2 < 2; d2++)
    #pragma unroll
    for (int r = 0; r < 16; r++) oacc[d2][r] = 0.0f;
  float rs = 0.0f;

  // tr-read per-lane base: d = dblk*32 + l31 -> D16 = dblk*2 + (l31>>4), col = lane&15
  const uint32_t sVb0 = (uint32_t)(size_t)(lu32_t*)&sV[0][0] +
                        (uint32_t)(hi * 1024 + ((lane >> 4) & 1) * 128 + (lane & 15) * 8);

  STAGE(0, 0);
  __syncthreads();

  int buf = 0;
  for (int kt = 0; kt < NT; kt++) {
    if (kt + 1 < NT) STAGE(buf ^ 1, kt + 1);

    // ---- K fragments (A-operand): row = kb2*32+l31, k = t*16+hi*8 ----
    short8 kbf[2][4];
    #pragma unroll
    for (int kb2 = 0; kb2 < 2; kb2++)
      #pragma unroll
      for (int t = 0; t < 4; t++) {
        int row = kb2 * 32 + l31;
        int gl = t * 2 + hi;
        kbf[kb2][t] = *(const short8*)&sK[buf][row * 64 + ((gl ^ (row & 7)) << 3)];
      }

    // ---- per 32-key block: S^T = K Q^T, exp2, pack to PV A-frags ----
    union u4s8 { uint32_t u[4]; short8 s; };
    u4s8 paf[4];   // A-frag for PV kstep 0..3 (keys 16*ks .. +15)
    #pragma unroll
    for (int kb2 = 0; kb2 < 2; kb2++) {
      f32x16 sc;
      #pragma unroll
      for (int r = 0; r < 16; r++) sc[r] = 0.0f;
      #pragma unroll
      for (int t = 0; t < 4; t++)
        sc = __builtin_amdgcn_mfma_f32_32x32x16_bf16(kbf[kb2][t], qa[t], sc, 0, 0, 0);

      float p[16];
      #pragma unroll
      for (int r = 0; r < 16; r++) {
        p[r] = __builtin_amdgcn_exp2f(sc[r]);
        rs += p[r];
      }
      uint32_t w[8];
      #pragma unroll
      for (int i = 0; i < 8; i++)
        asm("v_cvt_pk_bf16_f32 %0, %1, %2" : "=v"(w[i]) : "v"(p[2 * i]), "v"(p[2 * i + 1]));
      // half-exchange: after swap, (w0,w1,w2,w3) = operand words of kstep kb2*2,
      // (w4,w5,w6,w7) = kstep kb2*2+1  (derived from m74 C-layout + A-frag map)
      asm("v_permlane32_swap_b32 %0, %1" : "+v"(w[0]), "+v"(w[2]));
      asm("v_permlane32_swap_b32 %0, %1" : "+v"(w[1]), "+v"(w[3]));
      asm("v_permlane32_swap_b32 %0, %1" : "+v"(w[4]), "+v"(w[6]));
      asm("v_permlane32_swap_b32 %0, %1" : "+v"(w[5]), "+v"(w[7]));
      paf[kb2 * 2].u[0] = w[0]; paf[kb2 * 2].u[1] = w[1];
      paf[kb2 * 2].u[2] = w[2]; paf[kb2 * 2].u[3] = w[3];
      paf[kb2 * 2 + 1].u[0] = w[4]; paf[kb2 * 2 + 1].u[1] = w[5];
      paf[kb2 * 2 + 1].u[2] = w[6]; paf[kb2 * 2 + 1].u[3] = w[7];
    }

    // ---- V^T fragments (B-operand) via hardware transpose read ----
    u4s8 vb[2][4];
    {
      uint32_t tb = sVb0 + (uint32_t)(buf * 8192);
      #pragma unroll
      for (int d2 = 0; d2 < 2; d2++)
        #pragma unroll
        for (int ks = 0; ks < 4; ks++) {
          uint2 t0, t1;
          uint32_t a0 = tb + (uint32_t)(d2 * 256 + ks * 2048);
          asm volatile("ds_read_b64_tr_b16 %0, %1" : "=v"(t0) : "v"(a0));
          asm volatile("ds_read_b64_tr_b16 %0, %1" : "=v"(t1) : "v"(a0 + 512u));
          vb[d2][ks].u[0] = t0.x; vb[d2][ks].u[1] = t0.y;
          vb[d2][ks].u[2] = t1.x; vb[d2][ks].u[3] = t1.y;
        }
    }
    asm volatile("s_waitcnt lgkmcnt(0)" ::: "memory");
    __builtin_amdgcn_sched_barrier(0);

    // ---- O += P V ----
    #pragma unroll
    for (int d2 = 0; d2 < 2; d2++)
      #pragma unroll
      for (int ks = 0; ks < 4; ks++)
        oacc[d2] = __builtin_amdgcn_mfma_f32_32x32x16_bf16(paf[ks].s, vb[d2][ks].s, oacc[d2], 0, 0, 0);

    __syncthreads();
    buf ^= 1;
  }

  // ---- normalize + store ----
  float t = rs + __shfl_xor(rs, 32);   // total for q = l31
  float inv = 1.0f / t;
  float rq[16];
  #pragma unroll
  for (int r = 0; r < 16; r++) {
    int rho = (r & 3) + 8 * (r >> 2) + 4 * hi;   // q-row of C reg r
    rq[r] = __shfl(inv, rho);
  }

  unsigned short* Op = O + (size_t)b * SQL * DIMM + h * DHEAD;
  #pragma unroll
  for (int d2 = 0; d2 < 2; d2++)
    #pragma unroll
    for (int r = 0; r < 16; r++) {
      int rho = (r & 3) + 8 * (r >> 2) + 4 * hi;
      Op[(size_t)(qr0 + rho) * DIMM + d2 * 32 + l31] = f2bf(oacc[d2][r] * rq[r]);
    }
}

extern "C" void kernel_launch(void* const* d_in, const int* in_sizes, int n_in,
                              void* d_out, int out_size, void* d_ws, size_t ws_size,
                              hipStream_t stream) {
  (void)in_sizes; (void)n_in; (void)out_size; (void)ws_size;
  const float* x     = (const float*)d_in[0];
  const float* ctx   = (const float*)d_in[1];
  const float* gamma = (const float*)d_in[2];
  const float* beta  = (const float*)d_in[3];
  const float* w_q   = (const float*)d_in[4];
  const float* w_kv  = (const float*)d_in[5];
  const float* w_out = (const float*)d_in[6];
  const float* b_out = (const float*)d_in[7];
  const float* gate  = (const float*)d_in[8];
  float* out = (float*)d_out;
  char* ws = (char*)d_ws;

  unsigned short* XN   = (unsigned short*)(ws);                   // 8 MB  [4096][1024]
  unsigned short* QB   = (unsigned short*)(ws + (8ull  << 20));   // 8 MB  [4096][1024]
  unsigned short* CTXB = (unsigned short*)(ws + (16ull << 20));   // 16 MB [8192][1024]
  unsigned short* KVB  = (unsigned short*)(ws + (32ull << 20));   // 32 MB [8192][2048]
  unsigned short* OB   = (unsigned short*)(ws + (64ull << 20));   // 8 MB  [4096][1024]
  unsigned short* WQT  = (unsigned short*)(ws + (72ull << 20));   // 2 MB  [1024][1024]
  unsigned short* WKVT = (unsigned short*)(ws + (74ull << 20));   // 4 MB  [2048][1024]
  unsigned short* WOT  = (unsigned short*)(ws + (78ull << 20));   // 2 MB  [1024][1024]

  k_transpose_cast<<<dim3(32, 32), dim3(32, 8), 0, stream>>>(w_q, WQT, 1024, 1024);
  k_transpose_cast<<<dim3(64, 32), dim3(32, 8), 0, stream>>>(w_kv, WKVT, 1024, 2048);
  k_transpose_cast<<<dim3(32, 32), dim3(32, 8), 0, stream>>>(w_out, WOT, 1024, 1024);
  k_cast<<<dim3(8192), dim3(256), 0, stream>>>(ctx, CTXB);
  k_ln<<<dim3(4096), dim3(256), 0, stream>>>(x, gamma, beta, XN);
  k_gemm_bt<0><<<dim3(32, 8), dim3(256), 0, stream>>>(XN, WQT, QB, 4096, 1024, 1024, nullptr, nullptr);
  k_gemm_bt<0><<<dim3(64, 16), dim3(256), 0, stream>>>(CTXB, WKVT, KVB, 8192, 2048, 1024, nullptr, nullptr);
  k_attn<<<dim3(32, 32), dim3(128), 0, stream>>>(QB, KVB, OB);
  k_gemm_bt<1><<<dim3(32, 8), dim3(256), 0, stream>>>(OB, WOT, out, 4096, 1024, 1024, b_out, gate);
}

// Round 9
// 221.353 us; speedup vs baseline: 1.1626x; 1.1626x over previous
//
#include <hip/hip_runtime.h>
#include <hip/hip_bf16.h>
#include <stdint.h>

#define DIMM  1024
#define NHEAD 16
#define DHEAD 64
#define BB    2
#define SQL   2048
#define SKL   4096
#define KVW   2048   // kv row width = 2*INNER
#define NT    (SKL / 64)

typedef __attribute__((ext_vector_type(8))) short short8;
typedef __attribute__((ext_vector_type(4))) float f32x4;
typedef __attribute__((ext_vector_type(16))) float f32x16;
typedef __attribute__((ext_vector_type(4))) unsigned short us4;

typedef const __attribute__((address_space(1))) uint32_t gu32_t;
typedef __attribute__((address_space(3))) uint32_t lu32_t;

#define GLDS16(gp, lp) __builtin_amdgcn_global_load_lds((gu32_t*)(gp), (lu32_t*)(lp), 16, 0, 0)

static __device__ __forceinline__ unsigned short f2bf(float f) {
  union { float f; uint32_t u; } v; v.f = f;
  uint32_t r = v.u + 0x7fffu + ((v.u >> 16) & 1u);
  return (unsigned short)(r >> 16);
}

// ---------- weight transpose + cast: in f32 [K][N] -> out bf16 [N][K] ----------
__global__ __launch_bounds__(256) void k_transpose_cast(const float* __restrict__ in,
                                                        unsigned short* __restrict__ out,
                                                        int K, int N) {
  __shared__ float tile[32][33];
  int n0 = blockIdx.x * 32, k0 = blockIdx.y * 32;
  int tx = threadIdx.x, ty = threadIdx.y;
  #pragma unroll
  for (int i = 0; i < 4; i++)
    tile[ty + i * 8][tx] = in[(size_t)(k0 + ty + i * 8) * N + n0 + tx];
  __syncthreads();
  #pragma unroll
  for (int i = 0; i < 4; i++)
    out[(size_t)(n0 + ty + i * 8) * K + k0 + tx] = f2bf(tile[tx][ty + i * 8]);
}

// ---------- elementwise f32 -> bf16 (vectorized) ----------
__global__ __launch_bounds__(256) void k_cast(const float* __restrict__ in,
                                              unsigned short* __restrict__ out) {
  size_t i = (size_t)(blockIdx.x * 256 + threadIdx.x) * 4;
  float4 v = *(const float4*)(in + i);
  us4 o;
  o.x = f2bf(v.x); o.y = f2bf(v.y); o.z = f2bf(v.z); o.w = f2bf(v.w);
  *(us4*)(out + i) = o;
}

// ---------- LayerNorm + cast bf16: one block per row ----------
__global__ __launch_bounds__(256) void k_ln(const float* __restrict__ x,
                                            const float* __restrict__ gamma,
                                            const float* __restrict__ beta,
                                            unsigned short* __restrict__ out) {
  const int row = blockIdx.x, tid = threadIdx.x;
  const float* xr = x + (size_t)row * DIMM;
  float4 v = *(const float4*)(xr + tid * 4);
  float s = v.x + v.y + v.z + v.w;
  float ss = v.x * v.x + v.y * v.y + v.z * v.z + v.w * v.w;
  #pragma unroll
  for (int m = 1; m < 64; m <<= 1) {
    s += __shfl_xor(s, m);
    ss += __shfl_xor(ss, m);
  }
  __shared__ float red[8];
  const int wid = tid >> 6, lane = tid & 63;
  if (lane == 0) { red[wid] = s; red[4 + wid] = ss; }
  __syncthreads();
  s = red[0] + red[1] + red[2] + red[3];
  ss = red[4] + red[5] + red[6] + red[7];
  float mu = s * (1.0f / DIMM);
  float var = ss * (1.0f / DIMM) - mu * mu;
  float rstd = rsqrtf(var + 1e-5f);
  float4 g = *(const float4*)(gamma + tid * 4);
  float4 bt = *(const float4*)(beta + tid * 4);
  us4 o;
  o.x = f2bf((v.x - mu) * rstd * g.x + bt.x);
  o.y = f2bf((v.y - mu) * rstd * g.y + bt.y);
  o.z = f2bf((v.z - mu) * rstd * g.z + bt.z);
  o.w = f2bf((v.w - mu) * rstd * g.w + bt.w);
  *(us4*)(out + (size_t)row * DIMM + tid * 4) = o;
}

// ---------- 128x128x32 bf16 GEMM, B^T layout, 2-phase gload_lds pipeline ----------
// MODE 0: bf16 out.  MODE 1: f32 out, (acc + bias[col]) * tanh(gate[0]).
template<int MODE>
__global__ __launch_bounds__(256) void k_gemm_bt(const unsigned short* __restrict__ A,
                                                 const unsigned short* __restrict__ BT,
                                                 void* __restrict__ Cv,
                                                 int M, int N, int K,
                                                 const float* __restrict__ bias,
                                                 const float* __restrict__ gate) {
  __shared__ unsigned short lA[2][128 * 32];
  __shared__ unsigned short lB[2][128 * 32];
  const int tid = threadIdx.x;
  const int wid = tid >> 6, lane = tid & 63;
  const int kg = lane >> 4, lr = lane & 15;
  const int wr = wid >> 1, wc = wid & 1;
  const int im = blockIdx.x, in_ = blockIdx.y;
  const int nt = K >> 5;
  const size_t baseA = (size_t)im * 128 * K;
  const size_t baseB = (size_t)in_ * 128 * K;

  f32x4 acc[4][4];
  #pragma unroll
  for (int m = 0; m < 4; m++)
    #pragma unroll
    for (int n = 0; n < 4; n++) {
      f32x4 z = {0.0f, 0.0f, 0.0f, 0.0f};
      acc[m][n] = z;
    }

  // staging: LDS linear, global source pre-swizzled (granule ^ ((row>>1)&3))
  auto GSTAGE = [&](int bufi, int t) {
    int k0 = t << 5;
    #pragma unroll
    for (int j = 0; j < 2; j++) {
      int e = wid * 1024 + j * 512 + lane * 8;
      int row = e >> 5;
      int g = (e >> 3) & 3;
      int col = (g ^ ((row >> 1) & 3)) << 3;
      GLDS16(A + baseA + (size_t)row * K + k0 + col, &lA[bufi][e]);
      GLDS16(BT + baseB + (size_t)row * K + k0 + col, &lB[bufi][e]);
    }
  };

  GSTAGE(0, 0);
  __syncthreads();
  int buf = 0;
  for (int t = 0; t < nt; t++) {
    if (t + 1 < nt) GSTAGE(buf ^ 1, t + 1);
    short8 a[4], b[4];
    #pragma unroll
    for (int m = 0; m < 4; m++) {
      int row = wr * 64 + m * 16 + lr;
      a[m] = *(const short8*)&lA[buf][row * 32 + ((kg ^ ((row >> 1) & 3)) << 3)];
    }
    #pragma unroll
    for (int n = 0; n < 4; n++) {
      int row = wc * 64 + n * 16 + lr;
      b[n] = *(const short8*)&lB[buf][row * 32 + ((kg ^ ((row >> 1) & 3)) << 3)];
    }
    #pragma unroll
    for (int m = 0; m < 4; m++)
      #pragma unroll
      for (int n = 0; n < 4; n++)
        acc[m][n] = __builtin_amdgcn_mfma_f32_16x16x32_bf16(a[m], b[n], acc[m][n], 0, 0, 0);
    __syncthreads();
    buf ^= 1;
  }

  const int r0 = im * 128 + wr * 64;
  const int c0 = in_ * 128 + wc * 64;
  if constexpr (MODE == 0) {
    unsigned short* C = (unsigned short*)Cv;
    #pragma unroll
    for (int m = 0; m < 4; m++)
      #pragma unroll
      for (int n = 0; n < 4; n++)
        #pragma unroll
        for (int j = 0; j < 4; j++)
          C[(size_t)(r0 + m * 16 + kg * 4 + j) * N + c0 + n * 16 + lr] = f2bf(acc[m][n][j]);
  } else {
    float* C = (float*)Cv;
    float gl = tanhf(gate[0]);
    #pragma unroll
    for (int m = 0; m < 4; m++)
      #pragma unroll
      for (int n = 0; n < 4; n++)
        #pragma unroll
        for (int j = 0; j < 4; j++) {
          int col = c0 + n * 16 + lr;
          C[(size_t)(r0 + m * 16 + kg * 4 + j) * N + col] = (acc[m][n][j] + bias[col]) * gl;
        }
  }
}

// ---------- flash attention v9 ----------
// 64q/block, 4 waves = (2 q-waves x 2 k-waves), 256 threads, grid 1024 (flat,
// XCD-chunked swizzle: each XCD owns 4 bh -> KV fits its 4MB L2). Each wave:
// 32q (v8 in-register-P efficiency) x half of each 64-key tile (wk split) ->
// 4096 waves = 4 waves/SIMD TLP at v8's per-work LDS cost. Cross-wave (wk)
// O/rs reduction via LDS reuse at the end. 32x32x16 MFMA; swapped QK^T;
// cvt_pk+permlane32_swap in-register P->A-frag; V via ds_read_b64_tr_b16.
__global__ __launch_bounds__(256, 4) void k_attn(const unsigned short* __restrict__ Q,
                                                 const unsigned short* __restrict__ KV,
                                                 unsigned short* __restrict__ O) {
  __shared__ unsigned short sK[2][64 * 64];   // [key][d], granule-swizzled via source
  __shared__ unsigned short sV[2][64 * 64];   // subtiled [key/4][d/16][4][16]

  const int tid = threadIdx.x;
  const int wave = tid >> 6, lane = tid & 63;
  const int wq = wave & 1, wk = wave >> 1;
  const int l31 = lane & 31, hi = lane >> 5;

  // XCD-chunked swizzle: 1024 blocks, 8 XCDs, 128 blocks/XCD -> 4 bh per XCD
  const int wid_b = blockIdx.x;
  const int work = (wid_b & 7) * 128 + (wid_b >> 3);
  const int qb = work & 31, bh = work >> 5;
  const int b = bh >> 4, h = bh & 15;

  const unsigned short* Qp = Q + (size_t)b * SQL * DIMM + h * DHEAD;
  const unsigned short* Kp = KV + (size_t)b * SKL * KVW + h * DHEAD;
  const unsigned short* Vp = Kp + DIMM;

  const int qr0 = qb * 64 + wq * 32;

  // ---- staging geometry (loop-invariant), 256 threads x 2 granules each ----
  const unsigned short* ksrc[2]; int kdst[2];
  const unsigned short* vsrc[2]; int vdst[2];
  #pragma unroll
  for (int j = 0; j < 2; j++) {
    int e = (tid + j * 256) * 8;
    int row = e >> 6;
    int col = (((e >> 3) & 7) ^ (row & 7)) << 3;
    ksrc[j] = Kp + (size_t)row * KVW + col;
    kdst[j] = e;
    int g = tid + j * 256;
    int key = (g >> 5) * 4 + ((g >> 1) & 3);
    int d0v = ((g >> 3) & 3) * 16 + (g & 1) * 8;
    vsrc[j] = Vp + (size_t)key * KVW + d0v;
    vdst[j] = g * 8;
  }

  auto STAGE = [&](int bufi, int kt) {
    size_t off = (size_t)kt * 64 * KVW;
    #pragma unroll
    for (int j = 0; j < 2; j++) GLDS16(ksrc[j] + off, &sK[bufi][kdst[j]]);
    #pragma unroll
    for (int j = 0; j < 2; j++) GLDS16(vsrc[j] + off, &sV[bufi][vdst[j]]);
  };

  // Q fragments (B-operand of 32x32x16): lane holds Q[qr0+l31][t*16+hi*8 ..+7],
  // pre-scaled by SCALE*log2(e) so QK^T emits log2-domain logits.
  short8 qa[4];
  #pragma unroll
  for (int t = 0; t < 4; t++) {
    short8 v = *(const short8*)(Qp + (size_t)(qr0 + l31) * DIMM + t * 16 + hi * 8);
    #pragma unroll
    for (int j = 0; j < 8; j++) {
      union { float f; uint32_t u; } c;
      c.u = ((uint32_t)(unsigned short)v[j]) << 16;
      v[j] = (short)f2bf(c.f * 0.1803368801111f);  // 0.125 * log2(e)
    }
    qa[t] = v;
  }

  f32x16 oacc[2];
  #pragma unroll
  for (int d2 = 0; d2 < 2; d2++)
    #pragma unroll
    for (int r = 0; r < 16; r++) oacc[d2][r] = 0.0f;
  float rs = 0.0f;

  // tr-read per-lane base: d = d2*32 + l31 -> base has (l31>>4)*128 + (lane&15)*8
  const uint32_t sVb0 = (uint32_t)(size_t)(lu32_t*)&sV[0][0] +
                        (uint32_t)(hi * 1024 + ((lane >> 4) & 1) * 128 + (lane & 15) * 8);

  STAGE(0, 0);
  __syncthreads();

  union u4s8 { uint32_t u[4]; short8 s; };

  int buf = 0;
  for (int kt = 0; kt < NT; kt++) {
    if (kt + 1 < NT) STAGE(buf ^ 1, kt + 1);

    // ---- K fragments (A-operand): row = wk*32 + l31, k = t*16 + hi*8 ----
    short8 kbf[4];
    {
      int row = wk * 32 + l31;
      #pragma unroll
      for (int t = 0; t < 4; t++) {
        int gl = t * 2 + hi;
        kbf[t] = *(const short8*)&sK[buf][row * 64 + ((gl ^ (row & 7)) << 3)];
      }
    }

    // ---- S^T = K Q^T over this wave's 32-key half ----
    f32x16 sc;
    #pragma unroll
    for (int r = 0; r < 16; r++) sc[r] = 0.0f;
    #pragma unroll
    for (int t = 0; t < 4; t++)
      sc = __builtin_amdgcn_mfma_f32_32x32x16_bf16(kbf[t], qa[t], sc, 0, 0, 0);

    // ---- P = exp2, pack to PV A-frags in-register (v8-verified path) ----
    float p[16];
    #pragma unroll
    for (int r = 0; r < 16; r++) {
      p[r] = __builtin_amdgcn_exp2f(sc[r]);
      rs += p[r];
    }
    uint32_t w[8];
    #pragma unroll
    for (int i = 0; i < 8; i++)
      asm("v_cvt_pk_bf16_f32 %0, %1, %2" : "=v"(w[i]) : "v"(p[2 * i]), "v"(p[2 * i + 1]));
    asm("v_permlane32_swap_b32 %0, %1" : "+v"(w[0]), "+v"(w[2]));
    asm("v_permlane32_swap_b32 %0, %1" : "+v"(w[1]), "+v"(w[3]));
    asm("v_permlane32_swap_b32 %0, %1" : "+v"(w[4]), "+v"(w[6]));
    asm("v_permlane32_swap_b32 %0, %1" : "+v"(w[5]), "+v"(w[7]));
    u4s8 paf[2];
    paf[0].u[0] = w[0]; paf[0].u[1] = w[1]; paf[0].u[2] = w[2]; paf[0].u[3] = w[3];
    paf[1].u[0] = w[4]; paf[1].u[1] = w[5]; paf[1].u[2] = w[6]; paf[1].u[3] = w[7];

    // ---- V^T fragments (B-operand) via hardware transpose read ----
    u4s8 vb[2][2];
    {
      uint32_t tb = sVb0 + (uint32_t)(buf * 8192 + wk * 4096);
      #pragma unroll
      for (int d2 = 0; d2 < 2; d2++)
        #pragma unroll
        for (int ks = 0; ks < 2; ks++) {
          uint2 t0, t1;
          uint32_t a0 = tb + (uint32_t)(ks * 2048 + d2 * 256);
          asm volatile("ds_read_b64_tr_b16 %0, %1" : "=v"(t0) : "v"(a0));
          asm volatile("ds_read_b64_tr_b16 %0, %1" : "=v"(t1) : "v"(a0 + 512u));
          vb[d2][ks].u[0] = t0.x; vb[d2][ks].u[1] = t0.y;
          vb[d2][ks].u[2] = t1.x; vb[d2][ks].u[3] = t1.y;
        }
    }
    asm volatile("s_waitcnt lgkmcnt(0)" ::: "memory");
    __builtin_amdgcn_sched_barrier(0);

    // ---- O += P V (this wave's key-half partial) ----
    #pragma unroll
    for (int d2 = 0; d2 < 2; d2++)
      #pragma unroll
      for (int ks = 0; ks < 2; ks++)
        oacc[d2] = __builtin_amdgcn_mfma_f32_32x32x16_bf16(paf[ks].s, vb[d2][ks].s, oacc[d2], 0, 0, 0);

    __syncthreads();
    buf ^= 1;
  }

  // ---- cross-wave (wk) reduction via LDS reuse, then normalize + store ----
  float* sRed = (float*)&sK[0][0];   // 2(wq) x 2(d2) x 16(r) x 64(lane) f32 = 16KB
  float* sRs  = (float*)&sV[0][0];   // 2(wq) x 64 f32
  if (wk == 1) {
    #pragma unroll
    for (int d2 = 0; d2 < 2; d2++)
      #pragma unroll
      for (int r = 0; r < 16; r++)
        sRed[((wq * 2 + d2) * 16 + r) * 64 + lane] = oacc[d2][r];
    sRs[wq * 64 + lane] = rs;
  }
  __syncthreads();
  if (wk == 0) {
    #pragma unroll
    for (int d2 = 0; d2 < 2; d2++)
      #pragma unroll
      for (int r = 0; r < 16; r++)
        oacc[d2][r] += sRed[((wq * 2 + d2) * 16 + r) * 64 + lane];
    float rs2 = rs + sRs[wq * 64 + lane];
    float t = rs2 + __shfl_xor(rs2, 32);   // total for q = l31
    float inv = 1.0f / t;
    float rq[16];
    #pragma unroll
    for (int r = 0; r < 16; r++) {
      int rho = (r & 3) + 8 * (r >> 2) + 4 * hi;   // q-row of C reg r
      rq[r] = __shfl(inv, rho);
    }
    unsigned short* Op = O + (size_t)b * SQL * DIMM + h * DHEAD;
    #pragma unroll
    for (int d2 = 0; d2 < 2; d2++)
      #pragma unroll
      for (int r = 0; r < 16; r++) {
        int rho = (r & 3) + 8 * (r >> 2) + 4 * hi;
        Op[(size_t)(qr0 + rho) * DIMM + d2 * 32 + l31] = f2bf(oacc[d2][r] * rq[r]);
      }
  }
}

extern "C" void kernel_launch(void* const* d_in, const int* in_sizes, int n_in,
                              void* d_out, int out_size, void* d_ws, size_t ws_size,
                              hipStream_t stream) {
  (void)in_sizes; (void)n_in; (void)out_size; (void)ws_size;
  const float* x     = (const float*)d_in[0];
  const float* ctx   = (const float*)d_in[1];
  const float* gamma = (const float*)d_in[2];
  const float* beta  = (const float*)d_in[3];
  const float* w_q   = (const float*)d_in[4];
  const float* w_kv  = (const float*)d_in[5];
  const float* w_out = (const float*)d_in[6];
  const float* b_out = (const float*)d_in[7];
  const float* gate  = (const float*)d_in[8];
  float* out = (float*)d_out;
  char* ws = (char*)d_ws;

  unsigned short* XN   = (unsigned short*)(ws);                   // 8 MB  [4096][1024]
  unsigned short* QB   = (unsigned short*)(ws + (8ull  << 20));   // 8 MB  [4096][1024]
  unsigned short* CTXB = (unsigned short*)(ws + (16ull << 20));   // 16 MB [8192][1024]
  unsigned short* KVB  = (unsigned short*)(ws + (32ull << 20));   // 32 MB [8192][2048]
  unsigned short* OB   = (unsigned short*)(ws + (64ull << 20));   // 8 MB  [4096][1024]
  unsigned short* WQT  = (unsigned short*)(ws + (72ull << 20));   // 2 MB  [1024][1024]
  unsigned short* WKVT = (unsigned short*)(ws + (74ull << 20));   // 4 MB  [2048][1024]
  unsigned short* WOT  = (unsigned short*)(ws + (78ull << 20));   // 2 MB  [1024][1024]

  k_transpose_cast<<<dim3(32, 32), dim3(32, 8), 0, stream>>>(w_q, WQT, 1024, 1024);
  k_transpose_cast<<<dim3(64, 32), dim3(32, 8), 0, stream>>>(w_kv, WKVT, 1024, 2048);
  k_transpose_cast<<<dim3(32, 32), dim3(32, 8), 0, stream>>>(w_out, WOT, 1024, 1024);
  k_cast<<<dim3(8192), dim3(256), 0, stream>>>(ctx, CTXB);
  k_ln<<<dim3(4096), dim3(256), 0, stream>>>(x, gamma, beta, XN);
  k_gemm_bt<0><<<dim3(32, 8), dim3(256), 0, stream>>>(XN, WQT, QB, 4096, 1024, 1024, nullptr, nullptr);
  k_gemm_bt<0><<<dim3(64, 16), dim3(256), 0, stream>>>(CTXB, WKVT, KVB, 8192, 2048, 1024, nullptr, nullptr);
  k_attn<<<dim3(1024), dim3(256), 0, stream>>>(QB, KVB, OB);
  k_gemm_bt<1><<<dim3(32, 8), dim3(256), 0, stream>>>(OB, WOT, out, 4096, 1024, 1024, b_out, gate);
}